// Round 1
// baseline (655.520 us; speedup 1.0000x reference)
//
#include <hip/hip_runtime.h>
#include <hip/hip_bf16.h>
#include <stdint.h>

#define B_  4
#define S_  2048
#define E_  1280
#define H_  5
#define D_  256
#define BH_ 20
#define M_  8192
#define K_  1280

#define SCALE_ 0.027950849718747372f  // 1/sqrt(1280)

typedef __attribute__((ext_vector_type(8))) __bf16 bf16x8;
typedef __attribute__((ext_vector_type(4))) float  f32x4;

__device__ __forceinline__ ushort f2bf(float f) {
  union { float f; uint32_t u; } v; v.f = f;
  return (ushort)((v.u + 0x7FFFu + ((v.u >> 16) & 1u)) >> 16);
}

typedef const __attribute__((address_space(1))) void* gas_cvp;
typedef __attribute__((address_space(3))) void*       las_vp;

__device__ __forceinline__ void glds16(const void* g, void* l) {
  __builtin_amdgcn_global_load_lds((gas_cvp)g, (las_vp)l, 16, 0, 0);
}

// ---------------------------------------------------------------- convert
__global__ void cvt_bf16_kernel(const float4* __restrict__ in,
                                ushort4* __restrict__ out, int n4) {
  int i = blockIdx.x * blockDim.x + threadIdx.x;
  int stride = gridDim.x * blockDim.x;
  for (; i < n4; i += stride) {
    float4 v = in[i];
    ushort4 u;
    u.x = f2bf(v.x); u.y = f2bf(v.y); u.z = f2bf(v.z); u.w = f2bf(v.w);
    out[i] = u;
  }
}

// ---------------------------------------------------------------- GEMM
// C[m][n] = sum_k A[m][k] * W[n][k]   (A: M_ x K_,  W: 128-row tiles of N x K_)
// MODE 0: write bf16 to [bh][s][d] (Q/K layout)
// MODE 1: write bf16 to [bh][d][s] (V transposed)
// MODE 2: write f32 + bias to d_out [m][n]
template<int MODE>
__global__ __launch_bounds__(256, 2)
void gemm_bt(const ushort* __restrict__ A, const ushort* __restrict__ W,
             ushort* __restrict__ OB, float* __restrict__ OF,
             const float* __restrict__ bias)
{
  __shared__ __align__(16) ushort Abuf[128 * 64];
  __shared__ __align__(16) ushort Bbuf[128 * 64];
  const int tid  = threadIdx.x;
  const int lane = tid & 63;
  const int wid  = tid >> 6;
  const int m0 = blockIdx.x * 128;
  const int n0 = blockIdx.y * 128;
  const int wr = (wid >> 1) * 64;
  const int wc = (wid & 1) * 64;

  f32x4 acc[4][4] = {};

  const int soff = wid * 4096 + lane * 16;  // byte offset in 16KB tile

  for (int kk = 0; kk < K_; kk += 64) {
    __syncthreads();
#pragma unroll
    for (int i = 0; i < 4; ++i) {
      int off = soff + i * 1024;
      int row = off >> 7;              // 128 B per row (64 cols bf16)
      int c8  = (off >> 4) & 7;
      int s8  = c8 ^ (row & 7);        // inverse swizzle on global source
      glds16(A + (size_t)(m0 + row) * K_ + kk + s8 * 8,
             (char*)Abuf + wid * 4096 + i * 1024);
      glds16(W + (size_t)(n0 + row) * K_ + kk + s8 * 8,
             (char*)Bbuf + wid * 4096 + i * 1024);
    }
    __syncthreads();
#pragma unroll
    for (int kt = 0; kt < 2; ++kt) {
      bf16x8 af[4], bfr[4];
#pragma unroll
      for (int mf = 0; mf < 4; ++mf) {
        int row  = wr + mf * 16 + (lane & 15);
        int byte = (row << 7) + kt * 64 + ((lane >> 4) << 4);
        af[mf] = *(const bf16x8*)((const char*)Abuf + (byte ^ ((row & 7) << 4)));
      }
#pragma unroll
      for (int nf = 0; nf < 4; ++nf) {
        int row  = wc + nf * 16 + (lane & 15);
        int byte = (row << 7) + kt * 64 + ((lane >> 4) << 4);
        bfr[nf] = *(const bf16x8*)((const char*)Bbuf + (byte ^ ((row & 7) << 4)));
      }
#pragma unroll
      for (int mf = 0; mf < 4; ++mf)
#pragma unroll
        for (int nf = 0; nf < 4; ++nf)
          acc[mf][nf] = __builtin_amdgcn_mfma_f32_16x16x32_bf16(
              af[mf], bfr[nf], acc[mf][nf], 0, 0, 0);
    }
  }

  // epilogue
#pragma unroll
  for (int mf = 0; mf < 4; ++mf) {
#pragma unroll
    for (int nf = 0; nf < 4; ++nf) {
      int mbase = m0 + wr + mf * 16 + ((lane >> 4) << 2);
      int n     = n0 + wc + nf * 16 + (lane & 15);
      if (MODE == 2) {
        float bv = bias[n];
#pragma unroll
        for (int r = 0; r < 4; ++r) {
          int m = mbase + r;
          OF[(size_t)m * E_ + n] = acc[mf][nf][r] + bv;
        }
      } else if (MODE == 0) {
        int h = n >> 8, dd = n & 255;
#pragma unroll
        for (int r = 0; r < 4; ++r) {
          int m = mbase + r;
          int b = m >> 11, s = m & 2047;
          OB[((size_t)((b * H_ + h) * S_ + s)) * D_ + dd] = f2bf(acc[mf][nf][r]);
        }
      } else {  // MODE 1: Vt [bh][d][s]
        int h = n >> 8, dd = n & 255;
        int b = mbase >> 11, s = mbase & 2047;
        size_t idx = ((size_t)((mbase >> 11) * H_ + h) * D_ + dd) * S_ + (mbase & 2047);
        ushort4 pk;
        pk.x = f2bf(acc[mf][nf][0]);
        pk.y = f2bf(acc[mf][nf][1]);
        pk.z = f2bf(acc[mf][nf][2]);
        pk.w = f2bf(acc[mf][nf][3]);
        *(ushort4*)(OB + idx) = pk;
        (void)b; (void)s;
      }
    }
  }
}

// ---------------------------------------------------------------- flash attention
// Q,K: [bh][s][d] bf16; Vt: [bh][d][s] bf16; AO: [b][s][e] bf16
__global__ __launch_bounds__(256, 2)
void flash_attn_kernel(const ushort* __restrict__ Q, const ushort* __restrict__ Kg,
                       const ushort* __restrict__ Vt, ushort* __restrict__ AO)
{
  __shared__ __align__(16) ushort Kbuf[64 * 256];   // 32 KB (also hosts P after barrier)
  __shared__ __align__(16) ushort Vbuf[256 * 64];   // 32 KB (Vt tile)

  const int tid  = threadIdx.x;
  const int lane = tid & 63;
  const int wid  = tid >> 6;
  const int tq = gridDim.x - 1 - blockIdx.x;   // big tiles dispatch first
  const int bh = blockIdx.y;
  const int q0 = tq * 64;

  const ushort* Qb = Q  + (size_t)bh * S_ * D_;
  const ushort* Kb = Kg + (size_t)bh * S_ * D_;
  const ushort* Vb = Vt + (size_t)bh * D_ * S_;

  // Q fragments (wave's 16 rows, full d=256) hoisted to registers
  bf16x8 aq[8];
  {
    int qr = q0 + wid * 16 + (lane & 15);
    const ushort* qrow = Qb + (size_t)qr * D_ + ((lane >> 4) << 3);
#pragma unroll
    for (int kt = 0; kt < 8; ++kt) aq[kt] = *(const bf16x8*)(qrow + kt * 32);
  }

  f32x4 o[16] = {};
  float m_r[4], l_r[4];
#pragma unroll
  for (int r = 0; r < 4; ++r) { m_r[r] = -1e30f; l_r[r] = 0.f; }

  const int nt = tq + 1;
  for (int t = 0; t < nt; ++t) {
    const int kv0 = t * 64;
    __syncthreads();  // (a) previous iteration's LDS reads all done

    // stage K tile [64][256] and Vt tile [256][64], swizzled source
#pragma unroll
    for (int i = 0; i < 8; ++i) {
      int off = wid * 8192 + i * 1024 + lane * 16;
      {
        int row = off >> 9;
        int c8  = (off >> 4) & 31;
        int s8  = c8 ^ (row & 7);
        glds16(Kb + (size_t)(kv0 + row) * D_ + s8 * 8,
               (char*)Kbuf + wid * 8192 + i * 1024);
      }
      {
        int row = off >> 7;
        int c8  = (off >> 4) & 7;
        int s8  = c8 ^ (row & 7);
        glds16(Vb + (size_t)row * S_ + kv0 + s8 * 8,
               (char*)Vbuf + wid * 8192 + i * 1024);
      }
    }
    __syncthreads();  // (b) staging complete

    // S = Q K^T  (16 q-rows x 64 kv)
    f32x4 sacc[4] = {};
#pragma unroll
    for (int nf = 0; nf < 4; ++nf) {
      int n     = nf * 16 + (lane & 15);
      int rbase = (n << 9) + ((lane >> 4) << 4);
      int swz   = (n & 7) << 4;
#pragma unroll
      for (int kt = 0; kt < 8; ++kt) {
        bf16x8 bk = *(const bf16x8*)((const char*)Kbuf + ((rbase + kt * 64) ^ swz));
        sacc[nf] = __builtin_amdgcn_mfma_f32_16x16x32_bf16(aq[kt], bk, sacc[nf], 0, 0, 0);
      }
    }

    // online softmax (each lane: 4 rows r, cols = 16 lanes x 4 frags)
    const bool diag = (t == tq);
    float sv[4][4];
#pragma unroll
    for (int nf = 0; nf < 4; ++nf) {
      int kvc = kv0 + nf * 16 + (lane & 15);
#pragma unroll
      for (int r = 0; r < 4; ++r) {
        float s = sacc[nf][r] * SCALE_;
        if (diag) {
          int qr = q0 + wid * 16 + ((lane >> 4) << 2) + r;
          if (kvc > qr) s = -1e30f;
        }
        sv[nf][r] = s;
      }
    }
    float pm[4];
#pragma unroll
    for (int r = 0; r < 4; ++r)
      pm[r] = fmaxf(fmaxf(sv[0][r], sv[1][r]), fmaxf(sv[2][r], sv[3][r]));
#pragma unroll
    for (int d = 1; d < 16; d <<= 1)
#pragma unroll
      for (int r = 0; r < 4; ++r)
        pm[r] = fmaxf(pm[r], __shfl_xor(pm[r], d, 64));

    float alpha[4], rs[4];
#pragma unroll
    for (int r = 0; r < 4; ++r) {
      float mn = fmaxf(m_r[r], pm[r]);
      alpha[r] = __expf(m_r[r] - mn);
      m_r[r]   = mn;
    }
#pragma unroll
    for (int nf = 0; nf < 4; ++nf)
#pragma unroll
      for (int r = 0; r < 4; ++r)
        sv[nf][r] = __expf(sv[nf][r] - m_r[r]);
#pragma unroll
    for (int r = 0; r < 4; ++r)
      rs[r] = (sv[0][r] + sv[1][r]) + (sv[2][r] + sv[3][r]);
#pragma unroll
    for (int d = 1; d < 16; d <<= 1)
#pragma unroll
      for (int r = 0; r < 4; ++r)
        rs[r] += __shfl_xor(rs[r], d, 64);
#pragma unroll
    for (int r = 0; r < 4; ++r) l_r[r] = l_r[r] * alpha[r] + rs[r];
#pragma unroll
    for (int nf = 0; nf < 16; ++nf)
#pragma unroll
      for (int r = 0; r < 4; ++r) o[nf][r] *= alpha[r];

    __syncthreads();  // (c) all waves done reading Kbuf -> reuse head for P

    // write P (16x64 bf16) to per-wave region of Kbuf, swizzled
    char* Pw = (char*)Kbuf + wid * 2048;
#pragma unroll
    for (int nf = 0; nf < 4; ++nf)
#pragma unroll
      for (int r = 0; r < 4; ++r) {
        int row  = ((lane >> 4) << 2) + r;
        int col  = nf * 16 + (lane & 15);
        int byte = (row << 7) + (col << 1);
        *(ushort*)(Pw + (byte ^ ((row & 7) << 4))) = f2bf(sv[nf][r]);
      }

    // O += P V  (A-frags from P region, B-frags from Vt tile)
    bf16x8 pa[2];
    {
      int row   = lane & 15;
      int rbase = (row << 7) + ((lane >> 4) << 4);
      int swz   = (row & 7) << 4;
      pa[0] = *(const bf16x8*)(Pw + (rbase ^ swz));
      pa[1] = *(const bf16x8*)(Pw + ((rbase + 64) ^ swz));
    }
#pragma unroll
    for (int nf = 0; nf < 16; ++nf) {
      int n   = nf * 16 + (lane & 15);
      int rb  = (n << 7) + ((lane >> 4) << 4);
      int swz = (n & 7) << 4;
      o[nf] = __builtin_amdgcn_mfma_f32_16x16x32_bf16(
          pa[0], *(const bf16x8*)((const char*)Vbuf + (rb ^ swz)), o[nf], 0, 0, 0);
      o[nf] = __builtin_amdgcn_mfma_f32_16x16x32_bf16(
          pa[1], *(const bf16x8*)((const char*)Vbuf + ((rb + 64) ^ swz)), o[nf], 0, 0, 0);
    }
  }

  // epilogue: divide by l, write [b][s][h*256+dd] bf16
  float inv[4];
#pragma unroll
  for (int r = 0; r < 4; ++r) inv[r] = 1.0f / l_r[r];
  int b = bh / H_, h = bh % H_;
  const int dd0 = h * D_;
#pragma unroll
  for (int nf = 0; nf < 16; ++nf) {
    int dd = dd0 + nf * 16 + (lane & 15);
#pragma unroll
    for (int r = 0; r < 4; ++r) {
      int s = q0 + wid * 16 + ((lane >> 4) << 2) + r;
      AO[(size_t)(b * S_ + s) * E_ + dd] = f2bf(o[nf][r] * inv[r]);
    }
  }
}

// ---------------------------------------------------------------- launch
extern "C" void kernel_launch(void* const* d_in, const int* in_sizes, int n_in,
                              void* d_out, int out_size, void* d_ws, size_t ws_size,
                              hipStream_t stream) {
  const float* x  = (const float*)d_in[0];
  const float* Wq = (const float*)d_in[1];
  const float* Wk = (const float*)d_in[2];
  const float* Wv = (const float*)d_in[3];
  const float* Wu = (const float*)d_in[4];
  const float* bu = (const float*)d_in[5];

  char* ws = (char*)d_ws;
  ushort* xbf = (ushort*)(ws + 0);          // 8192x1280 bf16   (20.97 MB)
  ushort* Wqb = (ushort*)(ws + 20971520);   // 1280x1280 bf16
  ushort* Wkb = (ushort*)(ws + 24248320);
  ushort* Wvb = (ushort*)(ws + 27525120);
  ushort* Wub = (ushort*)(ws + 30801920);
  ushort* Qw  = (ushort*)(ws + 34078720);   // [20][2048][256]
  ushort* Kw  = (ushort*)(ws + 55050240);   // [20][2048][256]
  ushort* Vtw = (ushort*)(ws + 76021760);   // [20][256][2048]
  ushort* AOw = (ushort*)(ws + 96993280);   // [4][2048][1280]

  cvt_bf16_kernel<<<2048, 256, 0, stream>>>((const float4*)x,  (ushort4*)xbf, M_ * K_ / 4);
  cvt_bf16_kernel<<<800,  256, 0, stream>>>((const float4*)Wq, (ushort4*)Wqb, E_ * E_ / 4);
  cvt_bf16_kernel<<<800,  256, 0, stream>>>((const float4*)Wk, (ushort4*)Wkb, E_ * E_ / 4);
  cvt_bf16_kernel<<<800,  256, 0, stream>>>((const float4*)Wv, (ushort4*)Wvb, E_ * E_ / 4);
  cvt_bf16_kernel<<<800,  256, 0, stream>>>((const float4*)Wu, (ushort4*)Wub, E_ * E_ / 4);

  dim3 gg(M_ / 128, E_ / 128);  // 64 x 10
  gemm_bt<0><<<gg, 256, 0, stream>>>(xbf, Wqb, Qw,  nullptr, nullptr);
  gemm_bt<0><<<gg, 256, 0, stream>>>(xbf, Wkb, Kw,  nullptr, nullptr);
  gemm_bt<1><<<gg, 256, 0, stream>>>(xbf, Wvb, Vtw, nullptr, nullptr);

  flash_attn_kernel<<<dim3(S_ / 64, BH_), 256, 0, stream>>>(Qw, Kw, Vtw, AOw);

  gemm_bt<2><<<gg, 256, 0, stream>>>(AOw, Wub, nullptr, (float*)d_out, bu);
}